// Round 4
// baseline (2552.746 us; speedup 1.0000x reference)
//
#include <hip/hip_runtime.h>
#include <hip/hip_bf16.h>

// ---------------------------------------------------------------------------
// RNN: h_{t+1} = tanh(Wx[t] + h_t @ W_h + b_h),  Wx = X @ W_enc + b_enc
// T=512 B=128 D_IN=512 D_H=1024. fp16 MFMA (16x16x32), fp32 accumulate.
//
// R10: verified XCD-local exchange.
//   256 WGs (1/CU via 103KB LDS). group = wg&7 (XCD under round-robin
//   dispatch), 32 WGs/group own 16 batches; slice = wg>>3 owns 32 h-cols
//   (W_h slice pinned in LDS, K split across wave pairs + LDS reduction).
//   STARTUP PROBE: each WG publishes a magic via sc0 (L2-scope) store;
//   group members poll via sc0 loads. Mutual sc0 visibility <=> same L2.
//   Votes combined agent-scope; group unanimously picks:
//     FAST: exchange via sc0 stores/loads through the shared XCD L2
//           (~300cy RTs, ~4TB/s/XCD) - sound drained-flag protocol.
//     SLOW: R6-style fabric exchange (sc0 sc1) - known-good fallback.
//   Per step: poll (1 coalesced 256B flag load) -> 32KB slab read (16B
//   vector loads) -> LDS -> MFMA -> reduce -> tanh -> drained store ->
//   per-wave flag publish. 2 LDS barriers/step. Tags kept as backstop.
// ---------------------------------------------------------------------------

typedef _Float16 f16;
typedef f16 f16x8 __attribute__((ext_vector_type(8)));
typedef f16 f16x4 __attribute__((ext_vector_type(4)));
typedef float f32x4 __attribute__((ext_vector_type(4)));
typedef unsigned int u32x4 __attribute__((ext_vector_type(4)));
typedef unsigned long long u64;

#define T_STEPS 512
#define BATCH   128
#define D_IN    512
#define D_H     1024
#define BH      (BATCH * D_H)

// ---- workspace layout (bytes) ----
#define WX_OFF    0                         // fp16 Wx [512][128][1024] = 134217728
#define WENC_OFF  (134217728)               // fp16 W_encT [1024][512]  = 1048576
#define WH_OFF    (WENC_OFF + 1048576)      // fp16 W_hT   [1024][1024] = 2097152
#define HBUF_OFF  (WH_OFF + 2097152)        // fp16 hbuf [2][128][1024] = 524288
#define SYNC_OFF  (HBUF_OFF + 524288)       // flags 2KB + probe 1KB + ok 1KB

#define LDSTR   1032    // fp16 row stride (pad +8)

// tag bits: LSB of each fp16 lane of the 8B granule (backstop validation)
#define TAGM 0x0001000100010001ULL
__device__ __forceinline__ u64 tag_pat(int s) {
    return ((u64)(s & 1)        * 0x0000000100000001ULL)
         | ((u64)((s >> 1) & 1) * 0x0001000000010000ULL);
}

// ---- agent-scope atomics (fabric/MALL; used for the vote buffer) ----
__device__ __forceinline__ unsigned atom_ld4(const unsigned* p) {
    return __hip_atomic_load(p, __ATOMIC_RELAXED, __HIP_MEMORY_SCOPE_AGENT);
}
__device__ __forceinline__ void atom_st4(unsigned* p, unsigned v) {
    __hip_atomic_store(p, v, __ATOMIC_RELAXED, __HIP_MEMORY_SCOPE_AGENT);
}

// ---- scope-templated exchange ops: FAST = sc0 (XCD L2), SLOW = sc0 sc1 ----
template<bool FAST>
__device__ __forceinline__ void h_store8(void* p, u64 v) {
    if (FAST) asm volatile("global_store_dwordx2 %0, %1, off sc0"     :: "v"(p), "v"(v) : "memory");
    else      asm volatile("global_store_dwordx2 %0, %1, off sc0 sc1" :: "v"(p), "v"(v) : "memory");
}
template<bool FAST>
__device__ __forceinline__ void flag_store(unsigned* p, unsigned v) {
    if (FAST) asm volatile("global_store_dword %0, %1, off sc0"     :: "v"(p), "v"(v) : "memory");
    else      asm volatile("global_store_dword %0, %1, off sc0 sc1" :: "v"(p), "v"(v) : "memory");
}
template<bool FAST>
__device__ __forceinline__ unsigned flag_load(const unsigned* p) {
    unsigned v;
    if (FAST) asm volatile("global_load_dword %0, %1, off sc0"     : "=v"(v) : "v"(p));
    else      asm volatile("global_load_dword %0, %1, off sc0 sc1" : "=v"(v) : "v"(p));
    return v;
}
template<bool FAST>
__device__ __forceinline__ void slab_load16(u32x4& d, const void* p) {
    if (FAST) asm volatile("global_load_dwordx4 %0, %1, off sc0"     : "=v"(d) : "v"(p));
    else      asm volatile("global_load_dwordx4 %0, %1, off sc0 sc1" : "=v"(d) : "v"(p));
}

// rule-18 discipline: waitcnt then scheduling fence
#define VM0() do { \
    asm volatile("s_waitcnt vmcnt(0)" ::: "memory"); \
    __builtin_amdgcn_sched_barrier(0); } while (0)

#define BARRIER_LGKM() asm volatile("s_waitcnt lgkmcnt(0)\n\ts_barrier" ::: "memory")

__device__ __forceinline__ float fast_tanh(float v) {
    float ax = __builtin_fabsf(v);
    float tq = __builtin_amdgcn_exp2f(-2.8853900817779268f * ax);   // e^(-2|x|)
    float th = (1.0f - tq) * __builtin_amdgcn_rcpf(1.0f + tq);
    return __builtin_copysignf(th, v);
}

// ===========================================================================
// Phase 0: convert W_enc -> W_encT fp16, W_h -> W_hT fp16, h0 -> hbuf[0] fp16
// ===========================================================================
__global__ void convert_kernel(const float* __restrict__ Wenc,
                               const float* __restrict__ Wh,
                               const float* __restrict__ h0,
                               f16* __restrict__ WencT,
                               f16* __restrict__ WhT,
                               f16* __restrict__ hbuf0) {
    int idx = blockIdx.x * 256 + threadIdx.x;
    if (idx < D_IN * D_H) {                       // W_enc [512][1024]
        int k = idx >> 10, n = idx & 1023;
        WencT[n * D_IN + k] = (f16)Wenc[idx];
    } else if (idx < D_IN * D_H + D_H * D_H) {    // W_h [1024][1024]
        int j = idx - D_IN * D_H;
        int k = j >> 10, n = j & 1023;
        WhT[n * D_H + k] = (f16)Wh[j];
    } else if (idx < D_IN * D_H + D_H * D_H + BATCH * D_H) {
        int j = idx - (D_IN * D_H + D_H * D_H);
        f16 v = (f16)h0[j];
        unsigned short u = __builtin_bit_cast(unsigned short, v) & 0xFFFEu; // tag 0
        hbuf0[j] = __builtin_bit_cast(f16, u);
    }
}

// ===========================================================================
// Phase 1: Wx = X @ W_enc + b_enc   (M=65536, K=512, N=1024), out fp16
// ===========================================================================
__global__ __launch_bounds__(256, 2) void wx_gemm(
        const float* __restrict__ X,
        const f16*   __restrict__ WencT,
        const float* __restrict__ b_enc,
        f16*         __restrict__ Wx) {
    __shared__ f16 A_lds[128 * 72];
    __shared__ f16 B_lds[128 * 72];

    const int m0 = blockIdx.x * 128;
    const int n0 = blockIdx.y * 128;
    const int tid = threadIdx.x;
    const int wave = tid >> 6, lane = tid & 63;
    const int q = lane >> 4, r = lane & 15;
    const int wm = wave >> 1, wn = wave & 1;

    f32x4 acc[4][4] = {};

    for (int kb = 0; kb < D_IN; kb += 64) {
        #pragma unroll
        for (int i = 0; i < 8; ++i) {
            int vec = tid + i * 256;
            int m = vec >> 4, k4 = vec & 15;
            float4 f = *(const float4*)(X + (size_t)(m0 + m) * D_IN + kb + k4 * 4);
            f16x4 h4;
            h4[0] = (f16)f.x; h4[1] = (f16)f.y; h4[2] = (f16)f.z; h4[3] = (f16)f.w;
            *(f16x4*)(A_lds + m * 72 + k4 * 4) = h4;
        }
        #pragma unroll
        for (int i = 0; i < 4; ++i) {
            int vec = tid + i * 256;
            int n = vec >> 3, k8 = vec & 7;
            f16x8 v = *(const f16x8*)(WencT + (size_t)(n0 + n) * D_IN + kb + k8 * 8);
            *(f16x8*)(B_lds + n * 72 + k8 * 8) = v;
        }
        __syncthreads();
        #pragma unroll
        for (int ks = 0; ks < 2; ++ks) {
            f16x8 a[4], b[4];
            #pragma unroll
            for (int i = 0; i < 4; ++i)
                a[i] = *(const f16x8*)(A_lds + (wm * 64 + i * 16 + r) * 72 + ks * 32 + q * 8);
            #pragma unroll
            for (int j = 0; j < 4; ++j)
                b[j] = *(const f16x8*)(B_lds + (wn * 64 + j * 16 + r) * 72 + ks * 32 + q * 8);
            #pragma unroll
            for (int i = 0; i < 4; ++i)
                #pragma unroll
                for (int j = 0; j < 4; ++j)
                    acc[i][j] = __builtin_amdgcn_mfma_f32_16x16x32_f16(a[i], b[j], acc[i][j], 0, 0, 0);
        }
        __syncthreads();
    }
    #pragma unroll
    for (int j = 0; j < 4; ++j) {
        int col = n0 + wn * 64 + j * 16 + r;
        float be = b_enc[col];
        #pragma unroll
        for (int i = 0; i < 4; ++i) {
            int row = m0 + wm * 64 + i * 16 + q * 4;
            #pragma unroll
            for (int ii = 0; ii < 4; ++ii)
                Wx[(size_t)(row + ii) * D_H + col] = (f16)(acc[i][j][ii] + be);
        }
    }
}

// ===========================================================================
// Phase 2: scan. 256 WGs x 256 threads (1 WG/CU).
// ===========================================================================
extern __shared__ char smem_raw[];

__device__ __forceinline__ unsigned tag_bad(const u32x4* buf, u64 pat) {
    unsigned bad = 0;
    #pragma unroll
    for (int j = 0; j < 8; ++j) {
        u64 lo = ((u64)buf[j].y << 32) | buf[j].x;
        u64 hi = ((u64)buf[j].w << 32) | buf[j].z;
        bad |= ((((lo ^ pat) | (hi ^ pat)) & TAGM) ? 1u : 0u) << j;
    }
    return bad;
}

template<bool FAST>
__device__ __forceinline__ void scan_loop(
        const f16* __restrict__ Wx, const float* __restrict__ b_h,
        f16* __restrict__ hbuf, float* __restrict__ out,
        unsigned* __restrict__ gflags,
        f16* w_lds, f16* h_lds, float* red,
        int b0, int c0, int slc, int tid) {
    const int lane = tid & 63;
    const int wave = tid >> 6;
    const int q = lane >> 4, r = lane & 15;
    const int ct = wave & 1;                      // col-tile (16 cols)
    const int kh = wave >> 1;                     // K-half (512 each)
    const int colo  = c0 + ct * 16 + q * 4;       // lane's 4 consecutive cols
    const int batch = b0 + r;                     // lane's batch (kh==0 waves)
    const float4 bhv = *(const float4*)(b_h + colo);

    u32x4 buf[8];

    for (int t = 0; t < T_STEPS; ++t) {
        const u64 pat = tag_pat(t);
        const f16* hs = hbuf + (size_t)(t & 1) * BH + (size_t)b0 * D_H;

        // Wx prefetch (plain cached; only kh==0 waves consume it)
        f16x4 wxv = {};
        if (kh == 0)
            wxv = *(const f16x4*)(Wx + (size_t)t * BH + (size_t)batch * D_H + colo);

        // ---- readiness poll: all 64 group flag slots in one coalesced load.
        // Polling OWN slots too orders this wave against its own WG's kh0
        // publish (guards h_lds / red-slot reuse without a 3rd barrier).
        if (t > 0) {
            const unsigned tgt = (unsigned)t;
            for (;;) {
                unsigned v = flag_load<FAST>(gflags + lane);
                VM0();
                if (__ballot(v < tgt) == 0ull) break;
                __builtin_amdgcn_s_sleep(2);
            }
        }

        // ---- slab read: 16 batches x 2KB = 32KB, 8 x 16B per thread ----
        #pragma unroll
        for (int j = 0; j < 8; ++j) {
            int c = j * 256 + tid;                // chunk: row=c>>7, col=c&127
            slab_load16<FAST>(buf[j], hs + (size_t)(c >> 7) * D_H + (c & 127) * 8);
        }
        VM0();

        // tag backstop (sound flags => never fires)
        unsigned bad = tag_bad(buf, pat);
        while (__any(bad != 0)) {
            __builtin_amdgcn_s_sleep(2);
            #pragma unroll
            for (int j = 0; j < 8; ++j)
                if (bad & (1u << j)) {
                    int c = j * 256 + tid;
                    slab_load16<FAST>(buf[j], hs + (size_t)(c >> 7) * D_H + (c & 127) * 8);
                }
            VM0();
            bad = tag_bad(buf, pat);
        }

        // ---- h_t -> LDS ----
        #pragma unroll
        for (int j = 0; j < 8; ++j) {
            int c = j * 256 + tid;
            *(f16x8*)(h_lds + (c >> 7) * LDSTR + (c & 127) * 8) =
                __builtin_bit_cast(f16x8, buf[j]);
        }
        BARRIER_LGKM();

        // ---- MFMA: D[col][batch], K split across wave pairs ----
        const int kb = kh * 512;
        f32x4 acc0 = {0.f, 0.f, 0.f, 0.f}, acc1 = {0.f, 0.f, 0.f, 0.f};
        #pragma unroll
        for (int kk = 0; kk < 16; kk += 2) {
            f16x8 aw0 = *(const f16x8*)(w_lds + (ct * 16 + r) * LDSTR + kb + kk * 32 + q * 8);
            f16x8 ah0 = *(const f16x8*)(h_lds + r * LDSTR + kb + kk * 32 + q * 8);
            acc0 = __builtin_amdgcn_mfma_f32_16x16x32_f16(aw0, ah0, acc0, 0, 0, 0);
            f16x8 aw1 = *(const f16x8*)(w_lds + (ct * 16 + r) * LDSTR + kb + (kk + 1) * 32 + q * 8);
            f16x8 ah1 = *(const f16x8*)(h_lds + r * LDSTR + kb + (kk + 1) * 32 + q * 8);
            acc1 = __builtin_amdgcn_mfma_f32_16x16x32_f16(aw1, ah1, acc1, 0, 0, 0);
        }
        f32x4 accs = acc0 + acc1;

        // ---- cross-wave K reduction (parity-double-buffered slots) ----
        float* slot = red + (((t & 1) * 2 + ct) * 64 + lane) * 4;
        if (kh) *(f32x4*)slot = accs;
        BARRIER_LGKM();

        if (kh == 0) {
            f32x4 part = *(const f32x4*)slot;
            float th0 = fast_tanh(accs[0] + part[0] + (float)wxv[0] + bhv.x);
            float th1 = fast_tanh(accs[1] + part[1] + (float)wxv[1] + bhv.y);
            float th2 = fast_tanh(accs[2] + part[2] + (float)wxv[2] + bhv.z);
            float th3 = fast_tanh(accs[3] + part[3] + (float)wxv[3] + bhv.w);

            if (t < T_STEPS - 1) {
                f16x4 hv;
                hv[0] = (f16)th0; hv[1] = (f16)th1; hv[2] = (f16)th2; hv[3] = (f16)th3;
                u64 u = (__builtin_bit_cast(u64, hv) & ~TAGM) | tag_pat(t + 1);
                f16* hn = hbuf + (size_t)((t + 1) & 1) * BH;
                h_store8<FAST>(hn + (size_t)batch * D_H + colo, u);
                VM0();                      // ack at this mode's coherency point
                if (lane == 0)              // per-wave publish: slot slc*2+ct
                    flag_store<FAST>(gflags + slc * 2 + ct, (unsigned)(t + 1));
            } else {
                float4 o; o.x = th0; o.y = th1; o.z = th2; o.w = th3;
                *(float4*)(out + (size_t)batch * D_H + colo) = o;
            }
        }
    }
}

__global__ __launch_bounds__(256, 1) void rnn_steps(
        const f16*  __restrict__ WhT,    // [1024][1024] fp16 n-major
        const f16*  __restrict__ Wx,     // [512][128][1024] fp16
        const float* __restrict__ b_h,   // [1024]
        f16*        __restrict__ hbuf,   // [2][128][1024] fp16 (tagged)
        float*      __restrict__ out,    // [128][1024] fp32
        unsigned*   __restrict__ sync) { // flags[8][64] | probe[256] | ok[256]
    f16*   w_lds = (f16*)smem_raw;                       // [32][LDSTR] 66048B
    f16*   h_lds = (f16*)smem_raw + 32 * LDSTR;          // [16][LDSTR] 33024B
    float* red   = (float*)(smem_raw + 48 * LDSTR * 2);  // [2][2][64][4] 4096B

    const int wg   = blockIdx.x;
    const int grp  = wg & 7;                      // XCD id under round-robin
    const int slc  = wg >> 3;                     // column-slice id 0..31
    const int b0   = grp * 16;
    const int c0   = slc * 32;
    const int tid  = threadIdx.x;
    const int lane = tid & 63;
    const int wave = tid >> 6;

    unsigned* flags  = sync;                      // 512 dwords
    unsigned* probe  = sync + 512;                // 256 dwords
    unsigned* okbuf  = sync + 768;                // 256 dwords
    unsigned* gflags = flags + grp * 64;

    // pin W_h slice: 32 col-rows x 1024 k (64KB)
    #pragma unroll
    for (int i = 0; i < 16; ++i) {
        int vec = tid + i * 256;
        int n = vec >> 7, k8 = vec & 127;
        f16x8 v = *(const f16x8*)(WhT + (size_t)(c0 + n) * D_H + k8 * 8);
        *(f16x8*)(w_lds + n * LDSTR + k8 * 8) = v;
    }

    // ---- placement handshake: does the whole group share one L2? ----
    if (tid == 0) {
        unsigned m = 0xA5000000u | (unsigned)wg;
        asm volatile("global_store_dword %0, %1, off sc0" :: "v"(probe + wg), "v"(m) : "memory");
    }
    if (wave == 0) {
        int ok = 1, rounds = 0;
        for (;;) {
            unsigned v = 0;
            if (lane < 32) v = flag_load<true>(probe + (lane * 8 + grp));
            VM0();
            bool good = (lane >= 32) || (v == (0xA5000000u | (unsigned)(lane * 8 + grp)));
            if (__ballot(!good) == 0ull) break;
            if (++rounds > 1024) { ok = 0; break; }
            __builtin_amdgcn_s_sleep(4);
        }
        if (tid == 0) atom_st4(okbuf + wg, ok ? 2u : 1u);   // agent-scope vote
    }
    unsigned mv = 2;
    for (;;) {
        mv = 2;
        if (lane < 32) mv = atom_ld4(okbuf + (lane * 8 + grp));
        if (__ballot(mv == 0u) == 0ull) break;               // all votes in
        __builtin_amdgcn_s_sleep(4);
    }
    const bool fast = (__ballot(mv != 2u) == 0ull);          // unanimous
    __syncthreads();                                         // w_lds ready

    if (fast)
        scan_loop<true >(Wx, b_h, hbuf, out, gflags, w_lds, h_lds, red, b0, c0, slc, tid);
    else
        scan_loop<false>(Wx, b_h, hbuf, out, gflags, w_lds, h_lds, red, b0, c0, slc, tid);
}

// ===========================================================================
extern "C" void kernel_launch(void* const* d_in, const int* in_sizes, int n_in,
                              void* d_out, int out_size, void* d_ws, size_t ws_size,
                              hipStream_t stream) {
    const float* X     = (const float*)d_in[0];   // [512][128][512]
    const float* h0    = (const float*)d_in[1];   // [128][1024]
    const float* Wenc  = (const float*)d_in[2];   // [512][1024]
    const float* b_enc = (const float*)d_in[3];   // [1024]
    const float* Wh    = (const float*)d_in[4];   // [1024][1024]
    const float* b_h   = (const float*)d_in[5];   // [1024]
    float* out = (float*)d_out;

    char* ws = (char*)d_ws;
    f16* Wx16    = (f16*)(ws + WX_OFF);
    f16* WencT16 = (f16*)(ws + WENC_OFF);
    f16* WhT16   = (f16*)(ws + WH_OFF);
    f16* hbuf    = (f16*)(ws + HBUF_OFF);
    unsigned* sync = (unsigned*)(ws + SYNC_OFF);

    // zero h buffers (tag 0 everywhere: kills cross-launch tag collisions)
    // and the sync region (flags + probe + votes).
    hipMemsetAsync(hbuf, 0, 2 * (size_t)BH * 2, stream);
    hipMemsetAsync(sync, 0, 4096, stream);

    int total = D_IN * D_H + D_H * D_H + BATCH * D_H;
    convert_kernel<<<(total + 255) / 256, 256, 0, stream>>>(Wenc, Wh, h0,
                                                            WencT16, WhT16, hbuf);

    wx_gemm<<<dim3(65536 / 128, D_H / 128), 256, 0, stream>>>(X, WencT16, b_enc, Wx16);

    const int lds_bytes = 48 * LDSTR * 2 + 4096;   // 103168
    hipFuncSetAttribute((const void*)rnn_steps,
                        hipFuncAttributeMaxDynamicSharedMemorySize, lds_bytes);
    rnn_steps<<<256, 256, lds_bytes, stream>>>(WhT16, Wx16, b_h, hbuf, out, sync);
}

// Round 5
// 1963.352 us; speedup vs baseline: 1.3002x; 1.3002x over previous
//
#include <hip/hip_runtime.h>
#include <hip/hip_bf16.h>

// ---------------------------------------------------------------------------
// RNN: h_{t+1} = tanh(Wx[t] + h_t @ W_h + b_h),  Wx = X @ W_enc + b_enc
// T=512 B=128 D_IN=512 D_H=1024. fp16 MFMA (16x16x32), fp32 accumulate.
//
// R11 = R10 chassis (verified XCD-local exchange, FAST/SLOW probe) with the
// readiness channel DE-CONTENDED:
//   * one 64B cache line per flag writer (slot (slc*2+ct) at byte lane*64):
//     no write-write line sharing, 32KB flag region per-group-disjoint.
//   * ONE poller wave per WG (wave0, 64-lane line-gather) + release barrier;
//     poller fan-in per group drops 128 waves -> 32 waves.
//   * Wx[t+1] prefetched during step t's compute (HBM gather latency hidden
//     under MFMA + exchange instead of serialized inside the poll).
// Everything else identical to R10: sc0 L2-scope exchange when the startup
// probe proves the group shares one L2, fabric fallback otherwise; drained
// per-wave flag publish; period-4 tags as never-firing backstop.
// ---------------------------------------------------------------------------

typedef _Float16 f16;
typedef f16 f16x8 __attribute__((ext_vector_type(8)));
typedef f16 f16x4 __attribute__((ext_vector_type(4)));
typedef float f32x4 __attribute__((ext_vector_type(4)));
typedef unsigned int u32x4 __attribute__((ext_vector_type(4)));
typedef unsigned long long u64;

#define T_STEPS 512
#define BATCH   128
#define D_IN    512
#define D_H     1024
#define BH      (BATCH * D_H)

// ---- workspace layout (bytes) ----
#define WX_OFF    0                         // fp16 Wx [512][128][1024] = 134217728
#define WENC_OFF  (134217728)               // fp16 W_encT [1024][512]  = 1048576
#define WH_OFF    (WENC_OFF + 1048576)      // fp16 W_hT   [1024][1024] = 2097152
#define HBUF_OFF  (WH_OFF + 2097152)        // fp16 hbuf [2][128][1024] = 524288
#define SYNC_OFF  (HBUF_OFF + 524288)       // flags 32KB + probe 1KB + ok 1KB

#define LDSTR   1032    // fp16 row stride (pad +8)

// flag indexing: group g, slot s (0..63) -> dword (g*64 + s)*16  (64B/line)
#define FLG_DW_PER_GRP (64 * 16)

// tag bits: LSB of each fp16 lane of the 8B granule (backstop validation)
#define TAGM 0x0001000100010001ULL
__device__ __forceinline__ u64 tag_pat(int s) {
    return ((u64)(s & 1)        * 0x0000000100000001ULL)
         | ((u64)((s >> 1) & 1) * 0x0001000000010000ULL);
}

// ---- agent-scope atomics (fabric/MALL; used for the vote buffer) ----
__device__ __forceinline__ unsigned atom_ld4(const unsigned* p) {
    return __hip_atomic_load(p, __ATOMIC_RELAXED, __HIP_MEMORY_SCOPE_AGENT);
}
__device__ __forceinline__ void atom_st4(unsigned* p, unsigned v) {
    __hip_atomic_store(p, v, __ATOMIC_RELAXED, __HIP_MEMORY_SCOPE_AGENT);
}

// ---- scope-templated exchange ops: FAST = sc0 (XCD L2), SLOW = sc0 sc1 ----
template<bool FAST>
__device__ __forceinline__ void h_store8(void* p, u64 v) {
    if (FAST) asm volatile("global_store_dwordx2 %0, %1, off sc0"     :: "v"(p), "v"(v) : "memory");
    else      asm volatile("global_store_dwordx2 %0, %1, off sc0 sc1" :: "v"(p), "v"(v) : "memory");
}
template<bool FAST>
__device__ __forceinline__ void flag_store(unsigned* p, unsigned v) {
    if (FAST) asm volatile("global_store_dword %0, %1, off sc0"     :: "v"(p), "v"(v) : "memory");
    else      asm volatile("global_store_dword %0, %1, off sc0 sc1" :: "v"(p), "v"(v) : "memory");
}
template<bool FAST>
__device__ __forceinline__ unsigned flag_load(const unsigned* p) {
    unsigned v;
    if (FAST) asm volatile("global_load_dword %0, %1, off sc0"     : "=v"(v) : "v"(p));
    else      asm volatile("global_load_dword %0, %1, off sc0 sc1" : "=v"(v) : "v"(p));
    return v;
}
template<bool FAST>
__device__ __forceinline__ void slab_load16(u32x4& d, const void* p) {
    if (FAST) asm volatile("global_load_dwordx4 %0, %1, off sc0"     : "=v"(d) : "v"(p));
    else      asm volatile("global_load_dwordx4 %0, %1, off sc0 sc1" : "=v"(d) : "v"(p));
}

// rule-18 discipline: waitcnt then scheduling fence
#define VM0() do { \
    asm volatile("s_waitcnt vmcnt(0)" ::: "memory"); \
    __builtin_amdgcn_sched_barrier(0); } while (0)

#define BARRIER_LGKM() asm volatile("s_waitcnt lgkmcnt(0)\n\ts_barrier" ::: "memory")
#define BARRIER_PLAIN() asm volatile("s_barrier" ::: "memory")

__device__ __forceinline__ float fast_tanh(float v) {
    float ax = __builtin_fabsf(v);
    float tq = __builtin_amdgcn_exp2f(-2.8853900817779268f * ax);   // e^(-2|x|)
    float th = (1.0f - tq) * __builtin_amdgcn_rcpf(1.0f + tq);
    return __builtin_copysignf(th, v);
}

// ===========================================================================
// Phase 0: convert W_enc -> W_encT fp16, W_h -> W_hT fp16, h0 -> hbuf[0] fp16
// ===========================================================================
__global__ void convert_kernel(const float* __restrict__ Wenc,
                               const float* __restrict__ Wh,
                               const float* __restrict__ h0,
                               f16* __restrict__ WencT,
                               f16* __restrict__ WhT,
                               f16* __restrict__ hbuf0) {
    int idx = blockIdx.x * 256 + threadIdx.x;
    if (idx < D_IN * D_H) {                       // W_enc [512][1024]
        int k = idx >> 10, n = idx & 1023;
        WencT[n * D_IN + k] = (f16)Wenc[idx];
    } else if (idx < D_IN * D_H + D_H * D_H) {    // W_h [1024][1024]
        int j = idx - D_IN * D_H;
        int k = j >> 10, n = j & 1023;
        WhT[n * D_H + k] = (f16)Wh[j];
    } else if (idx < D_IN * D_H + D_H * D_H + BATCH * D_H) {
        int j = idx - (D_IN * D_H + D_H * D_H);
        f16 v = (f16)h0[j];
        unsigned short u = __builtin_bit_cast(unsigned short, v) & 0xFFFEu; // tag 0
        hbuf0[j] = __builtin_bit_cast(f16, u);
    }
}

// ===========================================================================
// Phase 1: Wx = X @ W_enc + b_enc   (M=65536, K=512, N=1024), out fp16
// ===========================================================================
__global__ __launch_bounds__(256, 2) void wx_gemm(
        const float* __restrict__ X,
        const f16*   __restrict__ WencT,
        const float* __restrict__ b_enc,
        f16*         __restrict__ Wx) {
    __shared__ f16 A_lds[128 * 72];
    __shared__ f16 B_lds[128 * 72];

    const int m0 = blockIdx.x * 128;
    const int n0 = blockIdx.y * 128;
    const int tid = threadIdx.x;
    const int wave = tid >> 6, lane = tid & 63;
    const int q = lane >> 4, r = lane & 15;
    const int wm = wave >> 1, wn = wave & 1;

    f32x4 acc[4][4] = {};

    for (int kb = 0; kb < D_IN; kb += 64) {
        #pragma unroll
        for (int i = 0; i < 8; ++i) {
            int vec = tid + i * 256;
            int m = vec >> 4, k4 = vec & 15;
            float4 f = *(const float4*)(X + (size_t)(m0 + m) * D_IN + kb + k4 * 4);
            f16x4 h4;
            h4[0] = (f16)f.x; h4[1] = (f16)f.y; h4[2] = (f16)f.z; h4[3] = (f16)f.w;
            *(f16x4*)(A_lds + m * 72 + k4 * 4) = h4;
        }
        #pragma unroll
        for (int i = 0; i < 4; ++i) {
            int vec = tid + i * 256;
            int n = vec >> 3, k8 = vec & 7;
            f16x8 v = *(const f16x8*)(WencT + (size_t)(n0 + n) * D_IN + kb + k8 * 8);
            *(f16x8*)(B_lds + n * 72 + k8 * 8) = v;
        }
        __syncthreads();
        #pragma unroll
        for (int ks = 0; ks < 2; ++ks) {
            f16x8 a[4], b[4];
            #pragma unroll
            for (int i = 0; i < 4; ++i)
                a[i] = *(const f16x8*)(A_lds + (wm * 64 + i * 16 + r) * 72 + ks * 32 + q * 8);
            #pragma unroll
            for (int j = 0; j < 4; ++j)
                b[j] = *(const f16x8*)(B_lds + (wn * 64 + j * 16 + r) * 72 + ks * 32 + q * 8);
            #pragma unroll
            for (int i = 0; i < 4; ++i)
                #pragma unroll
                for (int j = 0; j < 4; ++j)
                    acc[i][j] = __builtin_amdgcn_mfma_f32_16x16x32_f16(a[i], b[j], acc[i][j], 0, 0, 0);
        }
        __syncthreads();
    }
    #pragma unroll
    for (int j = 0; j < 4; ++j) {
        int col = n0 + wn * 64 + j * 16 + r;
        float be = b_enc[col];
        #pragma unroll
        for (int i = 0; i < 4; ++i) {
            int row = m0 + wm * 64 + i * 16 + q * 4;
            #pragma unroll
            for (int ii = 0; ii < 4; ++ii)
                Wx[(size_t)(row + ii) * D_H + col] = (f16)(acc[i][j][ii] + be);
        }
    }
}

// ===========================================================================
// Phase 2: scan. 256 WGs x 256 threads (1 WG/CU).
// ===========================================================================
extern __shared__ char smem_raw[];

__device__ __forceinline__ unsigned tag_bad(const u32x4* buf, u64 pat) {
    unsigned bad = 0;
    #pragma unroll
    for (int j = 0; j < 8; ++j) {
        u64 lo = ((u64)buf[j].y << 32) | buf[j].x;
        u64 hi = ((u64)buf[j].w << 32) | buf[j].z;
        bad |= ((((lo ^ pat) | (hi ^ pat)) & TAGM) ? 1u : 0u) << j;
    }
    return bad;
}

template<bool FAST>
__device__ __forceinline__ void scan_loop(
        const f16* __restrict__ Wx, const float* __restrict__ b_h,
        f16* __restrict__ hbuf, float* __restrict__ out,
        unsigned* __restrict__ gflags,
        f16* w_lds, f16* h_lds, float* red,
        int b0, int c0, int slc, int tid) {
    const int lane = tid & 63;
    const int wave = tid >> 6;
    const int q = lane >> 4, r = lane & 15;
    const int ct = wave & 1;                      // col-tile (16 cols)
    const int kh = wave >> 1;                     // K-half (512 each)
    const int colo  = c0 + ct * 16 + q * 4;       // lane's 4 consecutive cols
    const int batch = b0 + r;                     // lane's batch (kh==0 waves)
    const float4 bhv = *(const float4*)(b_h + colo);

    u32x4 buf[8];

    // Wx for step 0 (prefetched; steady-state prefetch is 1 step ahead)
    f16x4 wxv = {};
    if (kh == 0)
        wxv = *(const f16x4*)(Wx + (size_t)batch * D_H + colo);

    for (int t = 0; t < T_STEPS; ++t) {
        const u64 pat = tag_pat(t);
        const f16* hs = hbuf + (size_t)(t & 1) * BH + (size_t)b0 * D_H;

        // ---- readiness poll: ONE wave gathers all 64 per-line flag slots;
        // release barrier frees the rest. Poller waits on own WG's slots too
        // (orders h_lds/red reuse behind own kh0 epilogues).
        if (t > 0) {
            if (wave == 0) {
                const unsigned tgt = (unsigned)t;
                for (;;) {
                    unsigned v = flag_load<FAST>(gflags + lane * 16);
                    VM0();
                    if (__ballot(v < tgt) == 0ull) break;
                    __builtin_amdgcn_s_sleep(1);
                }
            }
            BARRIER_PLAIN();
        }

        // ---- slab read: 16 batches x 2KB = 32KB, 8 x 16B per thread ----
        #pragma unroll
        for (int j = 0; j < 8; ++j) {
            int c = j * 256 + tid;                // chunk: row=c>>7, col=c&127
            slab_load16<FAST>(buf[j], hs + (size_t)(c >> 7) * D_H + (c & 127) * 8);
        }
        VM0();

        // tag backstop (sound flags => never fires)
        unsigned bad = tag_bad(buf, pat);
        while (__any(bad != 0)) {
            __builtin_amdgcn_s_sleep(2);
            #pragma unroll
            for (int j = 0; j < 8; ++j)
                if (bad & (1u << j)) {
                    int c = j * 256 + tid;
                    slab_load16<FAST>(buf[j], hs + (size_t)(c >> 7) * D_H + (c & 127) * 8);
                }
            VM0();
            bad = tag_bad(buf, pat);
        }

        // ---- h_t -> LDS ----
        #pragma unroll
        for (int j = 0; j < 8; ++j) {
            int c = j * 256 + tid;
            *(f16x8*)(h_lds + (c >> 7) * LDSTR + (c & 127) * 8) =
                __builtin_bit_cast(f16x8, buf[j]);
        }
        BARRIER_LGKM();

        // ---- Wx prefetch for t+1: hidden under MFMA + exchange ----
        f16x4 wxv_nxt = {};
        if (kh == 0 && t + 1 < T_STEPS)
            wxv_nxt = *(const f16x4*)(Wx + (size_t)(t + 1) * BH
                                      + (size_t)batch * D_H + colo);

        // ---- MFMA: D[col][batch], K split across wave pairs ----
        const int kb = kh * 512;
        f32x4 acc0 = {0.f, 0.f, 0.f, 0.f}, acc1 = {0.f, 0.f, 0.f, 0.f};
        #pragma unroll
        for (int kk = 0; kk < 16; kk += 2) {
            f16x8 aw0 = *(const f16x8*)(w_lds + (ct * 16 + r) * LDSTR + kb + kk * 32 + q * 8);
            f16x8 ah0 = *(const f16x8*)(h_lds + r * LDSTR + kb + kk * 32 + q * 8);
            acc0 = __builtin_amdgcn_mfma_f32_16x16x32_f16(aw0, ah0, acc0, 0, 0, 0);
            f16x8 aw1 = *(const f16x8*)(w_lds + (ct * 16 + r) * LDSTR + kb + (kk + 1) * 32 + q * 8);
            f16x8 ah1 = *(const f16x8*)(h_lds + r * LDSTR + kb + (kk + 1) * 32 + q * 8);
            acc1 = __builtin_amdgcn_mfma_f32_16x16x32_f16(aw1, ah1, acc1, 0, 0, 0);
        }
        f32x4 accs = acc0 + acc1;

        // ---- cross-wave K reduction (parity-double-buffered slots) ----
        float* slot = red + (((t & 1) * 2 + ct) * 64 + lane) * 4;
        if (kh) *(f32x4*)slot = accs;
        BARRIER_LGKM();

        if (kh == 0) {
            f32x4 part = *(const f32x4*)slot;
            float th0 = fast_tanh(accs[0] + part[0] + (float)wxv[0] + bhv.x);
            float th1 = fast_tanh(accs[1] + part[1] + (float)wxv[1] + bhv.y);
            float th2 = fast_tanh(accs[2] + part[2] + (float)wxv[2] + bhv.z);
            float th3 = fast_tanh(accs[3] + part[3] + (float)wxv[3] + bhv.w);

            if (t < T_STEPS - 1) {
                f16x4 hv;
                hv[0] = (f16)th0; hv[1] = (f16)th1; hv[2] = (f16)th2; hv[3] = (f16)th3;
                u64 u = (__builtin_bit_cast(u64, hv) & ~TAGM) | tag_pat(t + 1);
                f16* hn = hbuf + (size_t)((t + 1) & 1) * BH;
                h_store8<FAST>(hn + (size_t)batch * D_H + colo, u);
                VM0();                      // ack at this mode's coherency point
                if (lane == 0)              // per-wave publish: own 64B line
                    flag_store<FAST>(gflags + (slc * 2 + ct) * 16, (unsigned)(t + 1));
            } else {
                float4 o; o.x = th0; o.y = th1; o.z = th2; o.w = th3;
                *(float4*)(out + (size_t)batch * D_H + colo) = o;
            }
        }
        wxv = wxv_nxt;
    }
}

__global__ __launch_bounds__(256, 1) void rnn_steps(
        const f16*  __restrict__ WhT,    // [1024][1024] fp16 n-major
        const f16*  __restrict__ Wx,     // [512][128][1024] fp16
        const float* __restrict__ b_h,   // [1024]
        f16*        __restrict__ hbuf,   // [2][128][1024] fp16 (tagged)
        float*      __restrict__ out,    // [128][1024] fp32
        unsigned*   __restrict__ sync) { // flags[8][64][16] | probe[256] | ok[256]
    f16*   w_lds = (f16*)smem_raw;                       // [32][LDSTR] 66048B
    f16*   h_lds = (f16*)smem_raw + 32 * LDSTR;          // [16][LDSTR] 33024B
    float* red   = (float*)(smem_raw + 48 * LDSTR * 2);  // [2][2][64][4] 4096B

    const int wg   = blockIdx.x;
    const int grp  = wg & 7;                      // XCD id under round-robin
    const int slc  = wg >> 3;                     // column-slice id 0..31
    const int b0   = grp * 16;
    const int c0   = slc * 32;
    const int tid  = threadIdx.x;
    const int lane = tid & 63;
    const int wave = tid >> 6;

    unsigned* flags  = sync;                      // 8*64*16 dwords (32KB)
    unsigned* probe  = sync + 8 * FLG_DW_PER_GRP; // 256 dwords
    unsigned* okbuf  = probe + 256;               // 256 dwords
    unsigned* gflags = flags + grp * FLG_DW_PER_GRP;

    // pin W_h slice: 32 col-rows x 1024 k (64KB)
    #pragma unroll
    for (int i = 0; i < 16; ++i) {
        int vec = tid + i * 256;
        int n = vec >> 7, k8 = vec & 127;
        f16x8 v = *(const f16x8*)(WhT + (size_t)(c0 + n) * D_H + k8 * 8);
        *(f16x8*)(w_lds + n * LDSTR + k8 * 8) = v;
    }

    // ---- placement handshake: does the whole group share one L2? ----
    if (tid == 0) {
        unsigned m = 0xA5000000u | (unsigned)wg;
        asm volatile("global_store_dword %0, %1, off sc0" :: "v"(probe + wg), "v"(m) : "memory");
    }
    if (wave == 0) {
        int ok = 1, rounds = 0;
        for (;;) {
            unsigned v = 0;
            if (lane < 32) v = flag_load<true>(probe + (lane * 8 + grp));
            VM0();
            bool good = (lane >= 32) || (v == (0xA5000000u | (unsigned)(lane * 8 + grp)));
            if (__ballot(!good) == 0ull) break;
            if (++rounds > 1024) { ok = 0; break; }
            __builtin_amdgcn_s_sleep(4);
        }
        if (tid == 0) atom_st4(okbuf + wg, ok ? 2u : 1u);   // agent-scope vote
    }
    unsigned mv = 2;
    for (;;) {
        mv = 2;
        if (lane < 32) mv = atom_ld4(okbuf + (lane * 8 + grp));
        if (__ballot(mv == 0u) == 0ull) break;               // all votes in
        __builtin_amdgcn_s_sleep(4);
    }
    const bool fast = (__ballot(mv != 2u) == 0ull);          // unanimous
    __syncthreads();                                         // w_lds ready

    if (fast)
        scan_loop<true >(Wx, b_h, hbuf, out, gflags, w_lds, h_lds, red, b0, c0, slc, tid);
    else
        scan_loop<false>(Wx, b_h, hbuf, out, gflags, w_lds, h_lds, red, b0, c0, slc, tid);
}

// ===========================================================================
extern "C" void kernel_launch(void* const* d_in, const int* in_sizes, int n_in,
                              void* d_out, int out_size, void* d_ws, size_t ws_size,
                              hipStream_t stream) {
    const float* X     = (const float*)d_in[0];   // [512][128][512]
    const float* h0    = (const float*)d_in[1];   // [128][1024]
    const float* Wenc  = (const float*)d_in[2];   // [512][1024]
    const float* b_enc = (const float*)d_in[3];   // [1024]
    const float* Wh    = (const float*)d_in[4];   // [1024][1024]
    const float* b_h   = (const float*)d_in[5];   // [1024]
    float* out = (float*)d_out;

    char* ws = (char*)d_ws;
    f16* Wx16    = (f16*)(ws + WX_OFF);
    f16* WencT16 = (f16*)(ws + WENC_OFF);
    f16* WhT16   = (f16*)(ws + WH_OFF);
    f16* hbuf    = (f16*)(ws + HBUF_OFF);
    unsigned* sync = (unsigned*)(ws + SYNC_OFF);

    // zero h buffers (tag 0 everywhere: kills cross-launch tag collisions)
    // and the sync region (flags + probe + votes).
    hipMemsetAsync(hbuf, 0, 2 * (size_t)BH * 2, stream);
    hipMemsetAsync(sync, 0, (8 * FLG_DW_PER_GRP + 512) * 4, stream);

    int total = D_IN * D_H + D_H * D_H + BATCH * D_H;
    convert_kernel<<<(total + 255) / 256, 256, 0, stream>>>(Wenc, Wh, h0,
                                                            WencT16, WhT16, hbuf);

    wx_gemm<<<dim3(65536 / 128, D_H / 128), 256, 0, stream>>>(X, WencT16, b_enc, Wx16);

    const int lds_bytes = 48 * LDSTR * 2 + 4096;   // 103168
    hipFuncSetAttribute((const void*)rnn_steps,
                        hipFuncAttributeMaxDynamicSharedMemorySize, lds_bytes);
    rnn_steps<<<256, 256, lds_bytes, stream>>>(WhT16, Wx16, b_h, hbuf, out, sync);
}